// Round 2
// baseline (10206.005 us; speedup 1.0000x reference)
//
#include <hip/hip_runtime.h>
#include <hip/hip_bf16.h>
#include <cstdint>
#include <cstddef>

#define TPB 256

static const int kBS = 16384;   // B*S = 32*512
static const int kD  = 512;
static const int kFF = 2048;
static const int kNX = 6;

// ---------------- pack one layer's QKV weights into [d][j], j: 0..511=Q, 512..1023=K, 1024..1535=V ----
__global__ void pack_qkv_k(const float* __restrict__ WQ, const float* __restrict__ WK,
                           const float* __restrict__ WV, float* __restrict__ wp, int l) {
    int idx = blockIdx.x * TPB + threadIdx.x;          // [0, 512*1536)
    int j = idx % 1536;
    int d = idx / 1536;
    int which = j >> 9;
    int r = j & 511;
    int h = r >> 6;
    int k = r & 63;
    const float* src = (which == 0) ? WQ : ((which == 1) ? WK : WV);
    wp[idx] = src[(size_t)(((l * 8 + h) * 512) + d) * 64 + k];
}

// ---------------- embedding: x[bs][d] = emb[tok[bs]][d] * 8 ----------------
__global__ void embed_k(const int* __restrict__ tok, const float* __restrict__ emb,
                        float* __restrict__ x) {
    int idx = blockIdx.x * TPB + threadIdx.x;   // float4 index, total kBS*kD/4
    int bs = idx >> 7;                           // 128 float4 per row
    int c4 = idx & 127;
    int t = tok[bs];
    float4 v = ((const float4*)emb)[(size_t)t * 128 + c4];
    v.x *= 8.f; v.y *= 8.f; v.z *= 8.f; v.w *= 8.f;
    ((float4*)x)[idx] = v;
}

// ---------------- fp32 tiled GEMM: C[M,N] = A[M,K] @ B[K,N] (+bias)(+res)(relu) ----------------
// flags: 1=bias, 2=relu, 4=residual
#define GBM 128
#define GBN 128
#define GBK 16

__global__ __launch_bounds__(256) void gemm_k(const float* __restrict__ A, const float* __restrict__ B,
                                              float* __restrict__ C, const float* __restrict__ bias,
                                              const float* __restrict__ res,
                                              int M, int N, int K, int flags) {
    __shared__ float As[GBK][GBM + 4];   // transposed store: As[k][row]
    __shared__ float Bs[GBK][GBN];
    int tid  = threadIdx.x;
    int bm   = blockIdx.x * GBM;
    int bn   = blockIdx.y * GBN;
    int trow = tid >> 4;            // 0..15
    int tcol = tid & 15;            // 0..15
    int arow = tid >> 2;            // 0..63
    int acol = (tid & 3) << 2;      // 0,4,8,12
    int brow = tid >> 5;            // 0..7
    int bcol = (tid & 31) << 2;     // 0..124

    float acc[8][8] = {};

    for (int k0 = 0; k0 < K; k0 += GBK) {
        float4 ga0 = *(const float4*)&A[(size_t)(bm + arow) * K + k0 + acol];
        float4 ga1 = *(const float4*)&A[(size_t)(bm + 64 + arow) * K + k0 + acol];
        float4 gb0 = *(const float4*)&B[(size_t)(k0 + brow) * N + bn + bcol];
        float4 gb1 = *(const float4*)&B[(size_t)(k0 + 8 + brow) * N + bn + bcol];
        __syncthreads();
        As[acol + 0][arow] = ga0.x; As[acol + 1][arow] = ga0.y;
        As[acol + 2][arow] = ga0.z; As[acol + 3][arow] = ga0.w;
        As[acol + 0][64 + arow] = ga1.x; As[acol + 1][64 + arow] = ga1.y;
        As[acol + 2][64 + arow] = ga1.z; As[acol + 3][64 + arow] = ga1.w;
        *(float4*)&Bs[brow][bcol]     = gb0;
        *(float4*)&Bs[brow + 8][bcol] = gb1;
        __syncthreads();
        #pragma unroll
        for (int k = 0; k < GBK; ++k) {
            float4 x0 = *(const float4*)&As[k][trow * 8];
            float4 x1 = *(const float4*)&As[k][trow * 8 + 4];
            float4 y0 = *(const float4*)&Bs[k][tcol * 8];
            float4 y1 = *(const float4*)&Bs[k][tcol * 8 + 4];
            float av[8] = {x0.x, x0.y, x0.z, x0.w, x1.x, x1.y, x1.z, x1.w};
            float bv[8] = {y0.x, y0.y, y0.z, y0.w, y1.x, y1.y, y1.z, y1.w};
            #pragma unroll
            for (int i = 0; i < 8; ++i)
                #pragma unroll
                for (int j = 0; j < 8; ++j)
                    acc[i][j] = fmaf(av[i], bv[j], acc[i][j]);
        }
    }

    int row0 = bm + trow * 8;
    int col0 = bn + tcol * 8;
    float bb[8] = {};
    if (flags & 1) {
        float4 c0 = *(const float4*)&bias[col0];
        float4 c1 = *(const float4*)&bias[col0 + 4];
        bb[0] = c0.x; bb[1] = c0.y; bb[2] = c0.z; bb[3] = c0.w;
        bb[4] = c1.x; bb[5] = c1.y; bb[6] = c1.z; bb[7] = c1.w;
    }
    #pragma unroll
    for (int i = 0; i < 8; ++i) {
        int row = row0 + i;
        float out[8];
        #pragma unroll
        for (int j = 0; j < 8; ++j) out[j] = acc[i][j] + bb[j];
        if (flags & 4) {
            float4 r0 = *(const float4*)&res[(size_t)row * N + col0];
            float4 r1 = *(const float4*)&res[(size_t)row * N + col0 + 4];
            out[0] += r0.x; out[1] += r0.y; out[2] += r0.z; out[3] += r0.w;
            out[4] += r1.x; out[5] += r1.y; out[6] += r1.z; out[7] += r1.w;
        }
        if (flags & 2) {
            #pragma unroll
            for (int j = 0; j < 8; ++j) out[j] = fmaxf(out[j], 0.f);
        }
        float4 w0 = {out[0], out[1], out[2], out[3]};
        float4 w1 = {out[4], out[5], out[6], out[7]};
        *(float4*)&C[(size_t)row * N + col0]     = w0;
        *(float4*)&C[(size_t)row * N + col0 + 4] = w1;
    }
}

// ---------------- fused attention: per (b,h), one thread per query row, online softmax ----------------
// qkv: [16384][1536] (Q|K|V each 512 = h*64+k). out: [16384][512] (h*64+v)
__global__ __launch_bounds__(256) void attn_k(const float* __restrict__ qkv, float* __restrict__ out) {
    __shared__ float Ks[16][64];
    __shared__ float Vs[16][64];
    int tid  = threadIdx.x;
    int half = blockIdx.x & 1;
    int h    = (blockIdx.x >> 1) & 7;
    int b    = blockIdx.x >> 4;
    int s    = half * 256 + tid;

    const float* Qp = qkv + (size_t)(b * 512 + s) * 1536 + h * 64;
    float q[64];
    #pragma unroll
    for (int d = 0; d < 64; d += 4) {
        float4 v = *(const float4*)&Qp[d];
        q[d] = v.x; q[d + 1] = v.y; q[d + 2] = v.z; q[d + 3] = v.w;
    }
    float o[64] = {};
    float m = -3.0e38f, l = 0.f;

    int lr = tid >> 4;            // 0..15
    int lc = (tid & 15) << 2;     // 0..60

    for (int t0 = 0; t0 < 512; t0 += 16) {
        __syncthreads();
        const float* Kp = qkv + (size_t)(b * 512 + t0 + lr) * 1536 + 512 + h * 64 + lc;
        *(float4*)&Ks[lr][lc] = *(const float4*)Kp;
        *(float4*)&Vs[lr][lc] = *(const float4*)(Kp + 512);
        __syncthreads();

        float sc[16];
        float tmax = -3.0e38f;
        #pragma unroll
        for (int t = 0; t < 16; ++t) {
            float sum = 0.f;
            #pragma unroll
            for (int d = 0; d < 64; ++d) sum = fmaf(q[d], Ks[t][d], sum);
            sum *= 0.125f;   // 1/sqrt(64)
            sc[t] = sum;
            tmax = fmaxf(tmax, sum);
        }
        float mnew = fmaxf(m, tmax);
        float scale = __expf(m - mnew);
        l *= scale;
        #pragma unroll
        for (int v = 0; v < 64; ++v) o[v] *= scale;
        #pragma unroll
        for (int t = 0; t < 16; ++t) {
            float e = __expf(sc[t] - mnew);
            l += e;
            #pragma unroll
            for (int v = 0; v < 64; ++v) o[v] = fmaf(e, Vs[t][v], o[v]);
        }
        m = mnew;
    }

    float inv = 1.f / l;
    float* Op = out + (size_t)(b * 512 + s) * 512 + h * 64;
    #pragma unroll
    for (int d = 0; d < 64; d += 4) {
        float4 v = {o[d] * inv, o[d + 1] * inv, o[d + 2] * inv, o[d + 3] * inv};
        *(float4*)&Op[d] = v;
    }
}

// ---------------- BatchNorm (training stats over 16384 rows, 512 channels) ----------------
// stage A: 128 blocks, each reduces 128 rows -> part[blk][512] (sum, sumsq)
__global__ void bn_part_k(const float* __restrict__ y, float* __restrict__ part) {
    int bid = blockIdx.x, tid = threadIdx.x;
    int c0 = tid, c1 = tid + 256;
    float s0 = 0, q0 = 0, s1 = 0, q1 = 0;
    const float* base = y + (size_t)bid * 128 * 512;
    for (int r = 0; r < 128; ++r) {
        float v0 = base[r * 512 + c0];
        float v1 = base[r * 512 + c1];
        s0 += v0; q0 = fmaf(v0, v0, q0);
        s1 += v1; q1 = fmaf(v1, v1, q1);
    }
    float2* p = (float2*)part;
    p[(size_t)bid * 512 + c0] = make_float2(s0, q0);
    p[(size_t)bid * 512 + c1] = make_float2(s1, q1);
}

// stage B: 1 block -> ss[c] = (scale, shift)
__global__ void bn_fin_k(const float* __restrict__ part, const float* __restrict__ g,
                         const float* __restrict__ be, float* __restrict__ ss) {
    int tid = threadIdx.x;
    for (int c = tid; c < 512; c += 256) {
        float s = 0.f, qq = 0.f;
        for (int bp = 0; bp < 128; ++bp) {
            float2 v = ((const float2*)part)[(size_t)bp * 512 + c];
            s += v.x; qq += v.y;
        }
        float mean = s * (1.f / 16384.f);
        float var  = qq * (1.f / 16384.f) - mean * mean;
        float scl  = g[c] * rsqrtf(var + 1e-5f);
        ((float2*)ss)[c] = make_float2(scl, be[c] - mean * scl);
    }
}

// apply: xo = y * scale[c] + shift[c]
__global__ void bn_apply_k(const float* __restrict__ y, const float* __restrict__ ss,
                           float* __restrict__ xo) {
    int idx = blockIdx.x * TPB + threadIdx.x;   // float4 idx
    int c4 = (idx & 127) << 2;
    float4 v = ((const float4*)y)[idx];
    float2 s0 = ((const float2*)ss)[c4];
    float2 s1 = ((const float2*)ss)[c4 + 1];
    float2 s2 = ((const float2*)ss)[c4 + 2];
    float2 s3 = ((const float2*)ss)[c4 + 3];
    v.x = fmaf(v.x, s0.x, s0.y);
    v.y = fmaf(v.y, s1.x, s1.y);
    v.z = fmaf(v.z, s2.x, s2.y);
    v.w = fmaf(v.w, s3.x, s3.y);
    ((float4*)xo)[idx] = v;
}

extern "C" void kernel_launch(void* const* d_in, const int* in_sizes, int n_in,
                              void* d_out, int out_size, void* d_ws, size_t ws_size,
                              hipStream_t stream) {
    const int*   tokens = (const int*)d_in[0];
    const float* emb    = (const float*)d_in[1];
    const float* WQ     = (const float*)d_in[2];
    const float* WK     = (const float*)d_in[3];
    const float* WV     = (const float*)d_in[4];
    const float* WO     = (const float*)d_in[5];
    const float* g1     = (const float*)d_in[6];
    const float* be1    = (const float*)d_in[7];
    const float* W1     = (const float*)d_in[8];
    const float* b1     = (const float*)d_in[9];
    const float* W2     = (const float*)d_in[10];
    const float* b2     = (const float*)d_in[11];
    const float* g2     = (const float*)d_in[12];
    const float* be2    = (const float*)d_in[13];

    // Workspace layout (floats), total ~171.4 MB:
    //   x    : 16384*512            (33.55 MB)  activations
    //   big  : 16384*2048           (134.22 MB) qkv[16384*1536]+attnout | ff
    //   wl   : 512*1536             (3.15 MB)   per-layer packed QKV weight
    //   part : 128*512*2            (0.52 MB)   BN partial sums
    //   ss   : 512*2                            BN scale/shift
    // y (pre-BN activations) lives in d_out (33.55 MB, rewritten every layer).
    float* xbuf  = (float*)d_ws;
    float* big   = xbuf + (size_t)kBS * kD;
    float* wl    = big  + (size_t)kBS * kFF;
    float* part  = wl   + (size_t)kD * 3 * kD;
    float* ssbuf = part + (size_t)128 * 512 * 2;

    float* ybuf    = (float*)d_out;
    float* qkv     = big;
    float* attnout = big + (size_t)kBS * 3 * kD;   // tail 33.5 MB of big
    float* ffbuf   = big;

    embed_k<<<(kBS * kD / 4) / TPB, TPB, 0, stream>>>(tokens, emb, xbuf);

    for (int l = 0; l < kNX; ++l) {
        // pack this layer's QKV weights: [512][1536]
        pack_qkv_k<<<(kD * 1536) / TPB, TPB, 0, stream>>>(WQ, WK, WV, wl, l);
        // QKV projection: [16384,512] @ [512,1536]
        gemm_k<<<dim3(kBS / GBM, 1536 / GBN), TPB, 0, stream>>>(
            xbuf, wl, qkv, nullptr, nullptr, kBS, 1536, kD, 0);
        // attention -> attnout[16384,512]
        attn_k<<<512, TPB, 0, stream>>>(qkv, attnout);
        // out projection + residual: y = attno @ WO + x
        gemm_k<<<dim3(kBS / GBM, kD / GBN), TPB, 0, stream>>>(
            attnout, WO + (size_t)l * kD * kD, ybuf, nullptr, xbuf, kBS, kD, kD, 4);
        // BN1 -> x
        bn_part_k<<<128, TPB, 0, stream>>>(ybuf, part);
        bn_fin_k<<<1, TPB, 0, stream>>>(part, g1 + l * kD, be1 + l * kD, ssbuf);
        bn_apply_k<<<(kBS * kD / 4) / TPB, TPB, 0, stream>>>(ybuf, ssbuf, xbuf);
        // FFN1: relu(x @ W1 + b1) -> ff   (qkv/attnout dead now)
        gemm_k<<<dim3(kBS / GBM, kFF / GBN), TPB, 0, stream>>>(
            xbuf, W1 + (size_t)l * kD * kFF, ffbuf, b1 + (size_t)l * kFF, nullptr, kBS, kFF, kD, 1 | 2);
        // FFN2 + residual: y = ff @ W2 + b2 + x
        gemm_k<<<dim3(kBS / GBM, kD / GBN), TPB, 0, stream>>>(
            ffbuf, W2 + (size_t)l * kFF * kD, ybuf, b2 + (size_t)l * kD, xbuf, kBS, kD, kFF, 1 | 4);
        // BN2 -> x (or in-place d_out on last layer)
        bn_part_k<<<128, TPB, 0, stream>>>(ybuf, part);
        bn_fin_k<<<1, TPB, 0, stream>>>(part, g2 + l * kD, be2 + l * kD, ssbuf);
        bn_apply_k<<<(kBS * kD / 4) / TPB, TPB, 0, stream>>>(
            ybuf, ssbuf, (l == kNX - 1) ? (float*)d_out : xbuf);
    }
}

// Round 4
// 5748.207 us; speedup vs baseline: 1.7755x; 1.7755x over previous
//
#include <hip/hip_runtime.h>
#include <hip/hip_bf16.h>
#include <cstdint>
#include <cstddef>

#define TPB 256

typedef unsigned short u16;
typedef short bf16x8 __attribute__((ext_vector_type(8)));
typedef float f32x4 __attribute__((ext_vector_type(4)));

static const int kBS = 16384;   // B*S = 32*512
static const int kD  = 512;
static const int kFF = 2048;
static const int kNX = 6;

// float -> bf16 round-to-nearest-even (no NaN inputs here)
__device__ __forceinline__ u16 f2bf(float f) {
    unsigned u = __builtin_bit_cast(unsigned, f);
    return (u16)((u + 0x7FFFu + ((u >> 16) & 1u)) >> 16);
}
__device__ __forceinline__ float bf2f(u16 x) {
    return __builtin_bit_cast(float, (unsigned)x << 16);
}

// async global->LDS, 16B per lane (dest must be linear: wave base + lane*16)
__device__ __forceinline__ void gld16(u16* lp, const u16* gp) {
    __builtin_amdgcn_global_load_lds((const __attribute__((address_space(1))) unsigned*)gp,
                                     (__attribute__((address_space(3))) unsigned*)lp,
                                     16, 0, 0);
}

// ---------------- embedding: x[bs][d] = emb[tok[bs]][d] * 8; fp32 + bf16 ----------------
__global__ void embed_k(const int* __restrict__ tok, const float* __restrict__ emb,
                        float* __restrict__ x, u16* __restrict__ xb) {
    int idx = blockIdx.x * TPB + threadIdx.x;   // float4 index, total kBS*kD/4
    int bs = idx >> 7;
    int c4 = idx & 127;
    int t = tok[bs];
    float4 v = ((const float4*)emb)[(size_t)t * 128 + c4];
    v.x *= 8.f; v.y *= 8.f; v.z *= 8.f; v.w *= 8.f;
    ((float4*)x)[idx] = v;
    ushort4 b4 = make_ushort4(f2bf(v.x), f2bf(v.y), f2bf(v.z), f2bf(v.w));
    *(ushort4*)&xb[(size_t)idx * 4] = b4;
}

// ---------------- weight packing (per layer), bf16 + transpose to [N][K] ----------------
// QKV: wp[j][k], j: 0..511=Q(h*64+dk), 512..1023=K, 1024..1535=V
__global__ void pack_qkvw_k(const float* __restrict__ WQ, const float* __restrict__ WK,
                            const float* __restrict__ WV, u16* __restrict__ wp, int l) {
    int idx = blockIdx.x * TPB + threadIdx.x;   // [0, 1536*512)
    int k = idx & 511, j = idx >> 9;
    int which = j >> 9, r = j & 511, h = r >> 6, dk = r & 63;
    const float* src = (which == 0) ? WQ : ((which == 1) ? WK : WV);
    wp[idx] = f2bf(src[(size_t)((l * 8 + h) * 512 + k) * 64 + dk]);
}

// generic transpose-pack: wt[n][k] = W[k][n], K=2^kbits rows, cols = N
__global__ void pack_t_k(const float* __restrict__ W, u16* __restrict__ wt,
                         int kbits, int cols) {
    int idx = blockIdx.x * TPB + threadIdx.x;
    int k = idx & ((1 << kbits) - 1);
    int n = idx >> kbits;
    wt[idx] = f2bf(W[(size_t)k * cols + n]);
}

// ---------------- bf16 MFMA GEMM: C[M,N] = A[M,K] @ Bt[N,K]^T ----------------
// flags: 1=bias(f32), 2=relu, 4=residual(f32), 8=bf16 out (else f32 out)
#define BM 128
#define BN 128
#define BK 32

__global__ __launch_bounds__(256) void gemm_bf16_k(
    const u16* __restrict__ A, const u16* __restrict__ Bt,
    float* __restrict__ Cf, u16* __restrict__ Cb,
    const float* __restrict__ bias, const float* __restrict__ res,
    int M, int N, int K, int flags)
{
    __shared__ u16 sA[2][BM * BK];
    __shared__ u16 sB[2][BN * BK];
    int tid = threadIdx.x;
    int bm = blockIdx.x * BM, bn = blockIdx.y * BN;
    int w = tid >> 6, l = tid & 63;
    int wr = (w >> 1) * 64, wc = (w & 1) * 64;   // wave's 64x64 sub-tile
    int lr = l & 15, lk = (l >> 4) * 8;          // frag row, frag k-offset

    f32x4 acc[4][4] = {};

    // 128x32 bf16 tile = 8KB = 512 x 16B chunks; 4 chunks per row:
    //   chunk c -> row = c>>2, k-offset = (c&3)*8
    int c1 = tid, c2 = tid + 256;
    int nt = K / BK;

    // prologue: stage tile 0
    gld16(&sA[0][c1 * 8], A  + (size_t)(bm + (c1 >> 2)) * K + (c1 & 3) * 8);
    gld16(&sA[0][c2 * 8], A  + (size_t)(bm + (c2 >> 2)) * K + (c2 & 3) * 8);
    gld16(&sB[0][c1 * 8], Bt + (size_t)(bn + (c1 >> 2)) * K + (c1 & 3) * 8);
    gld16(&sB[0][c2 * 8], Bt + (size_t)(bn + (c2 >> 2)) * K + (c2 & 3) * 8);
    __syncthreads();

    int buf = 0;
    for (int t = 0; t < nt; ++t) {
        if (t + 1 < nt) {
            int k0 = (t + 1) * BK;
            gld16(&sA[buf ^ 1][c1 * 8], A  + (size_t)(bm + (c1 >> 2)) * K + k0 + (c1 & 3) * 8);
            gld16(&sA[buf ^ 1][c2 * 8], A  + (size_t)(bm + (c2 >> 2)) * K + k0 + (c2 & 3) * 8);
            gld16(&sB[buf ^ 1][c1 * 8], Bt + (size_t)(bn + (c1 >> 2)) * K + k0 + (c1 & 3) * 8);
            gld16(&sB[buf ^ 1][c2 * 8], Bt + (size_t)(bn + (c2 >> 2)) * K + k0 + (c2 & 3) * 8);
        }
        bf16x8 af[4], bfr[4];
        #pragma unroll
        for (int i = 0; i < 4; ++i)
            af[i] = *(const bf16x8*)&sA[buf][(wr + i * 16 + lr) * BK + lk];
        #pragma unroll
        for (int j = 0; j < 4; ++j)
            bfr[j] = *(const bf16x8*)&sB[buf][(wc + j * 16 + lr) * BK + lk];
        #pragma unroll
        for (int i = 0; i < 4; ++i)
            #pragma unroll
            for (int j = 0; j < 4; ++j)
                acc[i][j] = __builtin_amdgcn_mfma_f32_16x16x32_bf16(af[i], bfr[j], acc[i][j], 0, 0, 0);
        __syncthreads();
        buf ^= 1;
    }

    // epilogue: D layout col=lane&15, row=(lane>>4)*4+reg  [m89-verified]
    int crow = (l >> 4) * 4;
    int ccol = l & 15;
    #pragma unroll
    for (int i = 0; i < 4; ++i) {
        #pragma unroll
        for (int j = 0; j < 4; ++j) {
            int col = bn + wc + j * 16 + ccol;
            float bv = (flags & 1) ? bias[col] : 0.f;
            #pragma unroll
            for (int r = 0; r < 4; ++r) {
                int row = bm + wr + i * 16 + crow + r;
                float v = acc[i][j][r] + bv;
                if (flags & 4) v += res[(size_t)row * N + col];
                if (flags & 2) v = fmaxf(v, 0.f);
                if (flags & 8) Cb[(size_t)row * N + col] = f2bf(v);
                else           Cf[(size_t)row * N + col] = v;
            }
        }
    }
}

// ---------------- fused attention (bf16 in/out, fp32 compute) ----------------
// qkv: [16384][1536] bf16 (Q|K|V each 512 = h*64+k). out: [16384][512] bf16
__global__ __launch_bounds__(256) void attn_k(const u16* __restrict__ qkv, u16* __restrict__ out) {
    __shared__ float Ks[16][64];
    __shared__ float Vs[16][64];
    int tid  = threadIdx.x;
    int half = blockIdx.x & 1;
    int h    = (blockIdx.x >> 1) & 7;
    int b    = blockIdx.x >> 4;
    int s    = half * 256 + tid;

    const u16* Qp = qkv + (size_t)(b * 512 + s) * 1536 + h * 64;
    float q[64];
    #pragma unroll
    for (int d = 0; d < 64; d += 4) {
        ushort4 uv = *(const ushort4*)&Qp[d];
        q[d]     = bf2f(uv.x) * 0.125f;   // fold 1/sqrt(64) into q
        q[d + 1] = bf2f(uv.y) * 0.125f;
        q[d + 2] = bf2f(uv.z) * 0.125f;
        q[d + 3] = bf2f(uv.w) * 0.125f;
    }
    float o[64] = {};
    float m = -3.0e38f, lsum = 0.f;

    int lr = tid >> 4;            // 0..15
    int lc = (tid & 15) << 2;     // 0..60

    for (int t0 = 0; t0 < 512; t0 += 16) {
        __syncthreads();
        const u16* Kp = qkv + (size_t)(b * 512 + t0 + lr) * 1536 + 512 + h * 64 + lc;
        ushort4 kv = *(const ushort4*)Kp;
        ushort4 vv = *(const ushort4*)(Kp + 512);
        *(float4*)&Ks[lr][lc] = make_float4(bf2f(kv.x), bf2f(kv.y), bf2f(kv.z), bf2f(kv.w));
        *(float4*)&Vs[lr][lc] = make_float4(bf2f(vv.x), bf2f(vv.y), bf2f(vv.z), bf2f(vv.w));
        __syncthreads();

        float sc[16];
        float tmax = -3.0e38f;
        #pragma unroll
        for (int t = 0; t < 16; ++t) {
            float sum = 0.f;
            #pragma unroll
            for (int d = 0; d < 64; ++d) sum = fmaf(q[d], Ks[t][d], sum);
            sc[t] = sum;
            tmax = fmaxf(tmax, sum);
        }
        float mnew = fmaxf(m, tmax);
        float scale = __expf(m - mnew);
        lsum *= scale;
        #pragma unroll
        for (int v = 0; v < 64; ++v) o[v] *= scale;
        #pragma unroll
        for (int t = 0; t < 16; ++t) {
            float e = __expf(sc[t] - mnew);
            lsum += e;
            #pragma unroll
            for (int v = 0; v < 64; ++v) o[v] = fmaf(e, Vs[t][v], o[v]);
        }
        m = mnew;
    }

    float inv = 1.f / lsum;
    u16* Op = out + (size_t)(b * 512 + s) * 512 + h * 64;
    #pragma unroll
    for (int d = 0; d < 64; d += 4) {
        ushort4 o4 = make_ushort4(f2bf(o[d] * inv), f2bf(o[d + 1] * inv),
                                  f2bf(o[d + 2] * inv), f2bf(o[d + 3] * inv));
        *(ushort4*)&Op[d] = o4;
    }
}

// ---------------- BatchNorm (training stats over 16384 rows, 512 channels) ----------------
// stage A: 256 blocks, each reduces 64 rows -> part[blk][512] (sum, sumsq)
__global__ void bn_part_k(const float* __restrict__ y, float* __restrict__ part) {
    int bid = blockIdx.x, tid = threadIdx.x;
    int c0 = tid, c1 = tid + 256;
    float s0 = 0, q0 = 0, s1 = 0, q1 = 0;
    const float* base = y + (size_t)bid * 64 * 512;
    for (int r = 0; r < 64; ++r) {
        float v0 = base[r * 512 + c0];
        float v1 = base[r * 512 + c1];
        s0 += v0; q0 = fmaf(v0, v0, q0);
        s1 += v1; q1 = fmaf(v1, v1, q1);
    }
    float2* p = (float2*)part;
    p[(size_t)bid * 512 + c0] = make_float2(s0, q0);
    p[(size_t)bid * 512 + c1] = make_float2(s1, q1);
}

// stage B: 1 block -> ss[c] = (scale, shift)
__global__ void bn_fin_k(const float* __restrict__ part, const float* __restrict__ g,
                         const float* __restrict__ be, float* __restrict__ ss) {
    int tid = threadIdx.x;
    for (int c = tid; c < 512; c += 256) {
        float s = 0.f, qq = 0.f;
        for (int bp = 0; bp < 256; ++bp) {
            float2 v = ((const float2*)part)[(size_t)bp * 512 + c];
            s += v.x; qq += v.y;
        }
        float mean = s * (1.f / 16384.f);
        float var  = qq * (1.f / 16384.f) - mean * mean;
        float scl  = g[c] * rsqrtf(var + 1e-5f);
        ((float2*)ss)[c] = make_float2(scl, be[c] - mean * scl);
    }
}

// apply: xo = y * scale[c] + shift[c]; optional bf16 shadow
__global__ void bn_apply_k(const float* __restrict__ y, const float* __restrict__ ss,
                           float* __restrict__ xo, u16* __restrict__ xb) {
    int idx = blockIdx.x * TPB + threadIdx.x;   // float4 idx
    int c4 = (idx & 127) << 2;
    float4 v = ((const float4*)y)[idx];
    float2 s0 = ((const float2*)ss)[c4];
    float2 s1 = ((const float2*)ss)[c4 + 1];
    float2 s2 = ((const float2*)ss)[c4 + 2];
    float2 s3 = ((const float2*)ss)[c4 + 3];
    v.x = fmaf(v.x, s0.x, s0.y);
    v.y = fmaf(v.y, s1.x, s1.y);
    v.z = fmaf(v.z, s2.x, s2.y);
    v.w = fmaf(v.w, s3.x, s3.y);
    ((float4*)xo)[idx] = v;
    if (xb) {
        ushort4 b4 = make_ushort4(f2bf(v.x), f2bf(v.y), f2bf(v.z), f2bf(v.w));
        *(ushort4*)&xb[(size_t)idx * 4] = b4;
    }
}

extern "C" void kernel_launch(void* const* d_in, const int* in_sizes, int n_in,
                              void* d_out, int out_size, void* d_ws, size_t ws_size,
                              hipStream_t stream) {
    const int*   tokens = (const int*)d_in[0];
    const float* emb    = (const float*)d_in[1];
    const float* WQ     = (const float*)d_in[2];
    const float* WK     = (const float*)d_in[3];
    const float* WV     = (const float*)d_in[4];
    const float* WO     = (const float*)d_in[5];
    const float* g1     = (const float*)d_in[6];
    const float* be1    = (const float*)d_in[7];
    const float* W1     = (const float*)d_in[8];
    const float* b1     = (const float*)d_in[9];
    const float* W2     = (const float*)d_in[10];
    const float* b2     = (const float*)d_in[11];
    const float* g2     = (const float*)d_in[12];
    const float* be2    = (const float*)d_in[13];

    // Workspace layout, total ~141.6 MB (proven-safe bound is >=171 MB):
    //   xbuf f32 33.55MB | xb bf16 16.78MB | big bf16 83.89MB | wqkvT 1.57 | woT 0.52 |
    //   w1T 2.10 | w2T 2.10 | part 1.05
    // big time-multiplexed: qkv[16384*1536] (QKV->attn) / ff[16384*2048] (FFN1->FFN2);
    // attnout at big+16384*2048 — disjoint from qkv (50.3MB) and ff (67.1MB) regions.
    char* p = (char*)d_ws;
    float* xbuf = (float*)p;  p += (size_t)kBS * kD * 4;
    u16*   xb   = (u16*)p;    p += (size_t)kBS * kD * 2;
    u16*   big  = (u16*)p;    p += ((size_t)kBS * kFF + (size_t)kBS * kD) * 2;
    u16*   wqkvT= (u16*)p;    p += (size_t)1536 * 512 * 2;
    u16*   woT  = (u16*)p;    p += (size_t)512 * 512 * 2;
    u16*   w1T  = (u16*)p;    p += (size_t)2048 * 512 * 2;
    u16*   w2T  = (u16*)p;    p += (size_t)512 * 2048 * 2;
    float* part = (float*)p;  p += (size_t)256 * 512 * 2 * 4;
    float* ssbuf= (float*)p;  p += (size_t)512 * 2 * 4;

    u16* qkvb  = big;
    u16* attno = big + (size_t)kBS * kFF;
    u16* ffb   = big;
    float* ybuf = (float*)d_out;

    embed_k<<<(kBS * kD / 4) / TPB, TPB, 0, stream>>>(tokens, emb, xbuf, xb);

    for (int l = 0; l < kNX; ++l) {
        // --- attention block ---
        pack_qkvw_k<<<(1536 * 512) / TPB, TPB, 0, stream>>>(WQ, WK, WV, wqkvT, l);
        gemm_bf16_k<<<dim3(kBS / BM, 1536 / BN), TPB, 0, stream>>>(
            xb, wqkvT, nullptr, qkvb, nullptr, nullptr, kBS, 1536, kD, 8);
        attn_k<<<512, TPB, 0, stream>>>(qkvb, attno);
        pack_t_k<<<(512 * 512) / TPB, TPB, 0, stream>>>(WO + (size_t)l * kD * kD, woT, 9, 512);
        gemm_bf16_k<<<dim3(kBS / BM, kD / BN), TPB, 0, stream>>>(
            attno, woT, ybuf, nullptr, nullptr, xbuf, kBS, kD, kD, 4);
        bn_part_k<<<256, TPB, 0, stream>>>(ybuf, part);
        bn_fin_k<<<1, TPB, 0, stream>>>(part, g1 + l * kD, be1 + l * kD, ssbuf);
        bn_apply_k<<<(kBS * kD / 4) / TPB, TPB, 0, stream>>>(ybuf, ssbuf, xbuf, xb);
        // --- FFN block ---
        pack_t_k<<<(2048 * 512) / TPB, TPB, 0, stream>>>(W1 + (size_t)l * kD * kFF, w1T, 9, 2048);
        gemm_bf16_k<<<dim3(kBS / BM, kFF / BN), TPB, 0, stream>>>(
            xb, w1T, nullptr, ffb, b1 + (size_t)l * kFF, nullptr, kBS, kFF, kD, 1 | 2 | 8);
        pack_t_k<<<(512 * 2048) / TPB, TPB, 0, stream>>>(W2 + (size_t)l * kFF * kD, w2T, 11, 512);
        gemm_bf16_k<<<dim3(kBS / BM, kD / BN), TPB, 0, stream>>>(
            ffb, w2T, ybuf, nullptr, b2 + (size_t)l * kD, xbuf, kBS, kD, kFF, 1 | 4);
        bn_part_k<<<256, TPB, 0, stream>>>(ybuf, part);
        bn_fin_k<<<1, TPB, 0, stream>>>(part, g2 + l * kD, be2 + l * kD, ssbuf);
        bn_apply_k<<<(kBS * kD / 4) / TPB, TPB, 0, stream>>>(
            ybuf, ssbuf, (l == kNX - 1) ? (float*)d_out : xbuf,
            (l == kNX - 1) ? nullptr : xb);
    }
}

// Round 5
// 2773.497 us; speedup vs baseline: 3.6798x; 2.0725x over previous
//
#include <hip/hip_runtime.h>
#include <hip/hip_bf16.h>
#include <cstdint>
#include <cstddef>

#define TPB 256

typedef unsigned short u16;
typedef short bf16x8 __attribute__((ext_vector_type(8)));
typedef float f32x4 __attribute__((ext_vector_type(4)));

static const int kBS = 16384;   // B*S = 32*512
static const int kD  = 512;
static const int kFF = 2048;
static const int kNX = 6;

// float -> bf16 round-to-nearest-even (no NaN inputs here)
__device__ __forceinline__ u16 f2bf(float f) {
    unsigned u = __builtin_bit_cast(unsigned, f);
    return (u16)((u + 0x7FFFu + ((u >> 16) & 1u)) >> 16);
}
__device__ __forceinline__ float bf2f(u16 x) {
    return __builtin_bit_cast(float, (unsigned)x << 16);
}

// async global->LDS, 16B per lane (dest must be linear: wave base + lane*16)
__device__ __forceinline__ void gld16(u16* lp, const u16* gp) {
    __builtin_amdgcn_global_load_lds((const __attribute__((address_space(1))) unsigned*)gp,
                                     (__attribute__((address_space(3))) unsigned*)lp,
                                     16, 0, 0);
}

// ---------------- embedding: x[bs][d] = emb[tok[bs]][d] * 8; fp32 + bf16 ----------------
__global__ void embed_k(const int* __restrict__ tok, const float* __restrict__ emb,
                        float* __restrict__ x, u16* __restrict__ xb) {
    int idx = blockIdx.x * TPB + threadIdx.x;   // float4 index, total kBS*kD/4
    int bs = idx >> 7;
    int c4 = idx & 127;
    int t = tok[bs];
    float4 v = ((const float4*)emb)[(size_t)t * 128 + c4];
    v.x *= 8.f; v.y *= 8.f; v.z *= 8.f; v.w *= 8.f;
    ((float4*)x)[idx] = v;
    ushort4 b4 = make_ushort4(f2bf(v.x), f2bf(v.y), f2bf(v.z), f2bf(v.w));
    *(ushort4*)&xb[(size_t)idx * 4] = b4;
}

// ---------------- weight packing (per layer), bf16 + transpose to [N][K] ----------------
// QKV: wp[j][k], j: 0..511=Q(h*64+dk), 512..1023=K, 1024..1535=V
__global__ void pack_qkvw_k(const float* __restrict__ WQ, const float* __restrict__ WK,
                            const float* __restrict__ WV, u16* __restrict__ wp, int l) {
    int idx = blockIdx.x * TPB + threadIdx.x;   // [0, 1536*512)
    int k = idx & 511, j = idx >> 9;
    int which = j >> 9, r = j & 511, h = r >> 6, dk = r & 63;
    const float* src = (which == 0) ? WQ : ((which == 1) ? WK : WV);
    wp[idx] = f2bf(src[(size_t)((l * 8 + h) * 512 + k) * 64 + dk]);
}

// generic transpose-pack: wt[n][k] = W[k][n], K=2^kbits rows, cols = N
__global__ void pack_t_k(const float* __restrict__ W, u16* __restrict__ wt,
                         int kbits, int cols) {
    int idx = blockIdx.x * TPB + threadIdx.x;
    int k = idx & ((1 << kbits) - 1);
    int n = idx >> kbits;
    wt[idx] = f2bf(W[(size_t)k * cols + n]);
}

// ---------------- bf16 MFMA GEMM: C[M,N] = A[M,K] @ Bt[N,K]^T ----------------
// flags: 1=bias(f32), 2=relu, 4=residual(f32), 8=bf16 out (else f32 out),
//        16=QKV scatter mode (cols<1024 -> Cb[row*1024+col]; cols>=1024 -> Vt[b][h][dv][s])
#define BM 128
#define BN 128
#define BK 32

__global__ __launch_bounds__(256) void gemm_bf16_k(
    const u16* __restrict__ A, const u16* __restrict__ Bt,
    float* __restrict__ Cf, u16* __restrict__ Cb, u16* __restrict__ Vt,
    const float* __restrict__ bias, const float* __restrict__ res,
    int M, int N, int K, int flags)
{
    __shared__ u16 sA[2][BM * BK];
    __shared__ u16 sB[2][BN * BK];
    int tid = threadIdx.x;
    int bm = blockIdx.x * BM, bn = blockIdx.y * BN;
    int w = tid >> 6, l = tid & 63;
    int wr = (w >> 1) * 64, wc = (w & 1) * 64;   // wave's 64x64 sub-tile
    int lr = l & 15, lk = (l >> 4) * 8;          // frag row, frag k-offset

    f32x4 acc[4][4] = {};

    // 128x32 bf16 tile = 8KB = 512 x 16B chunks; 4 chunks per row:
    //   chunk c -> row = c>>2, k-offset = (c&3)*8
    int c1 = tid, c2 = tid + 256;
    int nt = K / BK;

    // prologue: stage tile 0
    gld16(&sA[0][c1 * 8], A  + (size_t)(bm + (c1 >> 2)) * K + (c1 & 3) * 8);
    gld16(&sA[0][c2 * 8], A  + (size_t)(bm + (c2 >> 2)) * K + (c2 & 3) * 8);
    gld16(&sB[0][c1 * 8], Bt + (size_t)(bn + (c1 >> 2)) * K + (c1 & 3) * 8);
    gld16(&sB[0][c2 * 8], Bt + (size_t)(bn + (c2 >> 2)) * K + (c2 & 3) * 8);
    __syncthreads();

    int buf = 0;
    for (int t = 0; t < nt; ++t) {
        if (t + 1 < nt) {
            int k0 = (t + 1) * BK;
            gld16(&sA[buf ^ 1][c1 * 8], A  + (size_t)(bm + (c1 >> 2)) * K + k0 + (c1 & 3) * 8);
            gld16(&sA[buf ^ 1][c2 * 8], A  + (size_t)(bm + (c2 >> 2)) * K + k0 + (c2 & 3) * 8);
            gld16(&sB[buf ^ 1][c1 * 8], Bt + (size_t)(bn + (c1 >> 2)) * K + k0 + (c1 & 3) * 8);
            gld16(&sB[buf ^ 1][c2 * 8], Bt + (size_t)(bn + (c2 >> 2)) * K + k0 + (c2 & 3) * 8);
        }
        bf16x8 af[4], bfr[4];
        #pragma unroll
        for (int i = 0; i < 4; ++i)
            af[i] = *(const bf16x8*)&sA[buf][(wr + i * 16 + lr) * BK + lk];
        #pragma unroll
        for (int j = 0; j < 4; ++j)
            bfr[j] = *(const bf16x8*)&sB[buf][(wc + j * 16 + lr) * BK + lk];
        #pragma unroll
        for (int i = 0; i < 4; ++i)
            #pragma unroll
            for (int j = 0; j < 4; ++j)
                acc[i][j] = __builtin_amdgcn_mfma_f32_16x16x32_bf16(af[i], bfr[j], acc[i][j], 0, 0, 0);
        __syncthreads();
        buf ^= 1;
    }

    // epilogue: D layout col=lane&15, row=(lane>>4)*4+reg  [m89-verified]
    int crow = (l >> 4) * 4;
    int ccol = l & 15;

    if (flags & 16) {
        // QKV scatter: Q|K (col<1024) -> Cb[row*1024+col]; V -> Vt[((b*8+h)*64+dv)*512+s]
        #pragma unroll
        for (int i = 0; i < 4; ++i) {
            int row = bm + wr + i * 16 + crow;
            #pragma unroll
            for (int j = 0; j < 4; ++j) {
                int col = bn + wc + j * 16 + ccol;
                if (col < 1024) {
                    #pragma unroll
                    for (int r = 0; r < 4; ++r)
                        Cb[(size_t)(row + r) * 1024 + col] = f2bf(acc[i][j][r]);
                } else {
                    int dv = col - 1024;
                    ushort4 pk = make_ushort4(f2bf(acc[i][j][0]), f2bf(acc[i][j][1]),
                                              f2bf(acc[i][j][2]), f2bf(acc[i][j][3]));
                    *(ushort4*)&Vt[(((size_t)(row >> 9) * 8 + (dv >> 6)) * 64 + (dv & 63)) * 512
                                   + (row & 511)] = pk;
                }
            }
        }
        return;
    }

    #pragma unroll
    for (int i = 0; i < 4; ++i) {
        #pragma unroll
        for (int j = 0; j < 4; ++j) {
            int col = bn + wc + j * 16 + ccol;
            float bv = (flags & 1) ? bias[col] : 0.f;
            #pragma unroll
            for (int r = 0; r < 4; ++r) {
                int row = bm + wr + i * 16 + crow + r;
                float v = acc[i][j][r] + bv;
                if (flags & 4) v += res[(size_t)row * N + col];
                if (flags & 2) v = fmaxf(v, 0.f);
                if (flags & 8) Cb[(size_t)row * N + col] = f2bf(v);
                else           Cf[(size_t)row * N + col] = v;
            }
        }
    }
}

// ---------------- MFMA flash attention ----------------
// qk: [16384][1024] bf16 (Q|K, h*64+dk). vt: [256 bh][64 dv][512 s] bf16.
// out: [16384][512] bf16. Grid: 2048 blocks (qt 0..7, h 0..7, b 0..31), 256 thr (4 waves).
// Wave owns 16 q-rows. Per 32-t tile: 4 MFMA QK^T, in-reg softmax (t=lane&15,
// q=(lane>>4)*4+reg), P->bf16 via per-wave LDS (C-layout -> A-frag), 4 MFMA PV.
__global__ __launch_bounds__(256) void attn_mfma_k(const u16* __restrict__ qk,
                                                   const u16* __restrict__ vt,
                                                   u16* __restrict__ out) {
    __shared__ u16 Pl[4][16][40];   // per-wave P staging; stride 40 u16 = 80B (16B-aligned rows)
    int tid = threadIdx.x;
    int w = tid >> 6, l = tid & 63;
    int bid = blockIdx.x;
    int qt = bid & 7, h = (bid >> 3) & 7, b = bid >> 6;
    int q0 = qt * 64 + w * 16;
    int lr = l & 15, lk = l >> 4;   // lr: frag row / t-col; lk: k-slice group 0..3

    // Q fragments (A-layout): lane holds Q[q0+lr][lk*8 .. +8], k-halves 0/1
    const u16* qbase = qk + (size_t)(b * 512 + q0 + lr) * 1024 + h * 64 + lk * 8;
    bf16x8 qf0 = *(const bf16x8*)qbase;
    bf16x8 qf1 = *(const bf16x8*)(qbase + 32);

    const u16* kbase = qk + (size_t)(b * 512) * 1024 + 512 + h * 64 + lk * 8;
    const u16* vbase = vt + ((size_t)((b * 8 + h) * 64) + lr) * 512 + lk * 8;

    f32x4 O[4] = {};
    float m[4] = {-3.0e38f, -3.0e38f, -3.0e38f, -3.0e38f};
    float lsum[4] = {};

    u16* pw = &Pl[w][0][0];

    for (int t0 = 0; t0 < 512; t0 += 32) {
        // K fragments (B-layout): lane holds K[t0(+16)+lr][lk*8 .. +8]
        const u16* kr0 = kbase + (size_t)(t0 + lr) * 1024;
        const u16* kr1 = kbase + (size_t)(t0 + 16 + lr) * 1024;
        bf16x8 kf00 = *(const bf16x8*)kr0;
        bf16x8 kf01 = *(const bf16x8*)(kr0 + 32);
        bf16x8 kf10 = *(const bf16x8*)kr1;
        bf16x8 kf11 = *(const bf16x8*)(kr1 + 32);

        f32x4 S0 = {}, S1 = {};
        S0 = __builtin_amdgcn_mfma_f32_16x16x32_bf16(qf0, kf00, S0, 0, 0, 0);
        S0 = __builtin_amdgcn_mfma_f32_16x16x32_bf16(qf1, kf01, S0, 0, 0, 0);
        S1 = __builtin_amdgcn_mfma_f32_16x16x32_bf16(qf0, kf10, S1, 0, 0, 0);
        S1 = __builtin_amdgcn_mfma_f32_16x16x32_bf16(qf1, kf11, S1, 0, 0, 0);

        float tm[4], p0[4], p1[4], ps[4];
        #pragma unroll
        for (int r = 0; r < 4; ++r) {
            S0[r] *= 0.125f; S1[r] *= 0.125f;      // 1/sqrt(64)
            tm[r] = fmaxf(S0[r], S1[r]);
        }
        #pragma unroll
        for (int msk = 1; msk < 16; msk <<= 1)
            #pragma unroll
            for (int r = 0; r < 4; ++r)
                tm[r] = fmaxf(tm[r], __shfl_xor(tm[r], msk));
        #pragma unroll
        for (int r = 0; r < 4; ++r) {
            float mn = fmaxf(m[r], tm[r]);
            float fr = __expf(m[r] - mn);          // first iter: exp(-inf)=0
            lsum[r] *= fr;
            m[r] = mn;
            #pragma unroll
            for (int j = 0; j < 4; ++j) O[j][r] *= fr;
            p0[r] = __expf(S0[r] - mn);
            p1[r] = __expf(S1[r] - mn);
            ps[r] = p0[r] + p1[r];
        }
        #pragma unroll
        for (int msk = 1; msk < 16; msk <<= 1)
            #pragma unroll
            for (int r = 0; r < 4; ++r)
                ps[r] += __shfl_xor(ps[r], msk);
        #pragma unroll
        for (int r = 0; r < 4; ++r) lsum[r] += ps[r];

        // stage P (C-layout write: row q=lk*4+r, col t)
        #pragma unroll
        for (int r = 0; r < 4; ++r) {
            pw[(lk * 4 + r) * 40 + lr]      = f2bf(p0[r]);
            pw[(lk * 4 + r) * 40 + 16 + lr] = f2bf(p1[r]);
        }
        asm volatile("s_waitcnt lgkmcnt(0)" ::: "memory");
        // read P as A-fragment: lane holds P[lr][lk*8 .. +8]
        bf16x8 pf = *(const bf16x8*)&pw[lr * 40 + lk * 8];

        #pragma unroll
        for (int j = 0; j < 4; ++j) {
            bf16x8 vf = *(const bf16x8*)(vbase + (size_t)(j * 16) * 512 + t0);
            O[j] = __builtin_amdgcn_mfma_f32_16x16x32_bf16(pf, vf, O[j], 0, 0, 0);
        }
    }

    // epilogue: O C-layout row q=lk*4+r, col v=j*16+lr
    #pragma unroll
    for (int r = 0; r < 4; ++r) {
        float inv = 1.f / lsum[r];
        u16* orow = out + (size_t)(b * 512 + q0 + lk * 4 + r) * 512 + h * 64 + lr;
        #pragma unroll
        for (int j = 0; j < 4; ++j)
            orow[j * 16] = f2bf(O[j][r] * inv);
    }
}

// ---------------- BatchNorm (training stats over 16384 rows, 512 channels) ----------------
// stage A: 256 blocks, each reduces 64 rows -> part[blk][512] (sum, sumsq)
__global__ void bn_part_k(const float* __restrict__ y, float* __restrict__ part) {
    int bid = blockIdx.x, tid = threadIdx.x;
    int c0 = tid, c1 = tid + 256;
    float s0 = 0, q0 = 0, s1 = 0, q1 = 0;
    const float* base = y + (size_t)bid * 64 * 512;
    for (int r = 0; r < 64; ++r) {
        float v0 = base[r * 512 + c0];
        float v1 = base[r * 512 + c1];
        s0 += v0; q0 = fmaf(v0, v0, q0);
        s1 += v1; q1 = fmaf(v1, v1, q1);
    }
    float2* p = (float2*)part;
    p[(size_t)bid * 512 + c0] = make_float2(s0, q0);
    p[(size_t)bid * 512 + c1] = make_float2(s1, q1);
}

// stage B: 1 block -> ss[c] = (scale, shift)
__global__ void bn_fin_k(const float* __restrict__ part, const float* __restrict__ g,
                         const float* __restrict__ be, float* __restrict__ ss) {
    int tid = threadIdx.x;
    for (int c = tid; c < 512; c += 256) {
        float s = 0.f, qq = 0.f;
        for (int bp = 0; bp < 256; ++bp) {
            float2 v = ((const float2*)part)[(size_t)bp * 512 + c];
            s += v.x; qq += v.y;
        }
        float mean = s * (1.f / 16384.f);
        float var  = qq * (1.f / 16384.f) - mean * mean;
        float scl  = g[c] * rsqrtf(var + 1e-5f);
        ((float2*)ss)[c] = make_float2(scl, be[c] - mean * scl);
    }
}

// apply: xo = y * scale[c] + shift[c]; optional bf16 shadow
__global__ void bn_apply_k(const float* __restrict__ y, const float* __restrict__ ss,
                           float* __restrict__ xo, u16* __restrict__ xb) {
    int idx = blockIdx.x * TPB + threadIdx.x;   // float4 idx
    int c4 = (idx & 127) << 2;
    float4 v = ((const float4*)y)[idx];
    float2 s0 = ((const float2*)ss)[c4];
    float2 s1 = ((const float2*)ss)[c4 + 1];
    float2 s2 = ((const float2*)ss)[c4 + 2];
    float2 s3 = ((const float2*)ss)[c4 + 3];
    v.x = fmaf(v.x, s0.x, s0.y);
    v.y = fmaf(v.y, s1.x, s1.y);
    v.z = fmaf(v.z, s2.x, s2.y);
    v.w = fmaf(v.w, s3.x, s3.y);
    ((float4*)xo)[idx] = v;
    if (xb) {
        ushort4 b4 = make_ushort4(f2bf(v.x), f2bf(v.y), f2bf(v.z), f2bf(v.w));
        *(ushort4*)&xb[(size_t)idx * 4] = b4;
    }
}

extern "C" void kernel_launch(void* const* d_in, const int* in_sizes, int n_in,
                              void* d_out, int out_size, void* d_ws, size_t ws_size,
                              hipStream_t stream) {
    const int*   tokens = (const int*)d_in[0];
    const float* emb    = (const float*)d_in[1];
    const float* WQ     = (const float*)d_in[2];
    const float* WK     = (const float*)d_in[3];
    const float* WV     = (const float*)d_in[4];
    const float* WO     = (const float*)d_in[5];
    const float* g1     = (const float*)d_in[6];
    const float* be1    = (const float*)d_in[7];
    const float* W1     = (const float*)d_in[8];
    const float* b1     = (const float*)d_in[9];
    const float* W2     = (const float*)d_in[10];
    const float* b2     = (const float*)d_in[11];
    const float* g2     = (const float*)d_in[12];
    const float* be2    = (const float*)d_in[13];

    // Workspace (~125 MB):
    //   xbuf f32 33.55 | xb bf16 16.78 | big bf16 67.11 | wqkvT 1.57 | woT 0.52 |
    //   w1T 2.10 | w2T 2.10 | part 1.05 | ss
    // big = [qkb 33.55 | vt 16.78 | attno 16.78], ff overlays big (QKV data dead by FFN1).
    char* p = (char*)d_ws;
    float* xbuf = (float*)p;  p += (size_t)kBS * kD * 4;
    u16*   xb   = (u16*)p;    p += (size_t)kBS * kD * 2;
    u16*   big  = (u16*)p;    p += (size_t)kBS * kFF * 2;
    u16*   wqkvT= (u16*)p;    p += (size_t)1536 * 512 * 2;
    u16*   woT  = (u16*)p;    p += (size_t)512 * 512 * 2;
    u16*   w1T  = (u16*)p;    p += (size_t)2048 * 512 * 2;
    u16*   w2T  = (u16*)p;    p += (size_t)512 * 2048 * 2;
    float* part = (float*)p;  p += (size_t)256 * 512 * 2 * 4;
    float* ssbuf= (float*)p;  p += (size_t)512 * 2 * 4;

    u16* qkb   = big;
    u16* vtb   = big + (size_t)kBS * 1024;
    u16* attno = vtb + (size_t)256 * 64 * 512;
    u16* ffb   = big;
    float* ybuf = (float*)d_out;

    embed_k<<<(kBS * kD / 4) / TPB, TPB, 0, stream>>>(tokens, emb, xbuf, xb);

    for (int l = 0; l < kNX; ++l) {
        // --- attention block ---
        pack_qkvw_k<<<(1536 * 512) / TPB, TPB, 0, stream>>>(WQ, WK, WV, wqkvT, l);
        gemm_bf16_k<<<dim3(kBS / BM, 1536 / BN), TPB, 0, stream>>>(
            xb, wqkvT, nullptr, qkb, vtb, nullptr, nullptr, kBS, 1536, kD, 16);
        attn_mfma_k<<<2048, TPB, 0, stream>>>(qkb, vtb, attno);
        pack_t_k<<<(512 * 512) / TPB, TPB, 0, stream>>>(WO + (size_t)l * kD * kD, woT, 9, 512);
        gemm_bf16_k<<<dim3(kBS / BM, kD / BN), TPB, 0, stream>>>(
            attno, woT, ybuf, nullptr, nullptr, nullptr, xbuf, kBS, kD, kD, 4);
        bn_part_k<<<256, TPB, 0, stream>>>(ybuf, part);
        bn_fin_k<<<1, TPB, 0, stream>>>(part, g1 + l * kD, be1 + l * kD, ssbuf);
        bn_apply_k<<<(kBS * kD / 4) / TPB, TPB, 0, stream>>>(ybuf, ssbuf, xbuf, xb);
        // --- FFN block ---
        pack_t_k<<<(2048 * 512) / TPB, TPB, 0, stream>>>(W1 + (size_t)l * kD * kFF, w1T, 9, 2048);
        gemm_bf16_k<<<dim3(kBS / BM, kFF / BN), TPB, 0, stream>>>(
            xb, w1T, nullptr, ffb, nullptr, b1 + (size_t)l * kFF, nullptr, kBS, kFF, kD, 1 | 2 | 8);
        pack_t_k<<<(512 * 2048) / TPB, TPB, 0, stream>>>(W2 + (size_t)l * kFF * kD, w2T, 11, 512);
        gemm_bf16_k<<<dim3(kBS / BM, kD / BN), TPB, 0, stream>>>(
            ffb, w2T, ybuf, nullptr, nullptr, b2 + (size_t)l * kD, xbuf, kBS, kD, kFF, 1 | 4);
        bn_part_k<<<256, TPB, 0, stream>>>(ybuf, part);
        bn_fin_k<<<1, TPB, 0, stream>>>(part, g2 + l * kD, be2 + l * kD, ssbuf);
        bn_apply_k<<<(kBS * kD / 4) / TPB, TPB, 0, stream>>>(
            ybuf, ssbuf, (l == kNX - 1) ? (float*)d_out : xbuf,
            (l == kNX - 1) ? nullptr : xb);
    }
}